// Round 11
// baseline (36.389 us; speedup 1.0000x reference)
//
#include <hip/hip_runtime.h>
#include <hip/hip_bf16.h>

// Oja scan, reformulated. G[b][n][t] = row_n . x_t for n in [0,1088):
// rows 0..1023 = W0 rows, rows 1024..1087 = X rows (=> S = X X^T).
// Scan: exact projected Oja recurrence on u[j] = W_t . x_j:
//   y_t = sigmoid(u[t]);  u <- (1-lr*y^2)*u + (lr*y)*S[t,:]
// R11: kill the f32 staging path in gemm.
//   k0 (cvt): W,X -> bf16 once (streaming, BW-bound).
//   k1 (gemm): panel staged via global_load_lds (linear LDS dest, zero
//       VALU/VGPR payload) with 3-bit XOR bank-swizzle applied as
//       pre-swizzled per-lane GLOBAL source + swizzled read base
//       (phys = logical ^ ((row&7)<<4)); inner loop = ds_read_b128 +
//       16B global B + MFMA, swizzle folded into two base pointers.
//   k2 (scan): unchanged from R10 (lane-parallel, ~4 us).

#define BB 8
#define TT 64
#define NI 1024
#define NO 1024
#define NTOT 1088            // 1024 W rows + 64 X rows
#define NTILES 68            // NTOT/16

typedef __attribute__((ext_vector_type(8))) short bf16x8;
typedef __attribute__((ext_vector_type(8))) short short8v;
typedef __attribute__((ext_vector_type(4))) float f32x4;

__device__ __forceinline__ short f2bf(float f) {
    __hip_bfloat16 h = __float2bfloat16(f);
    return __builtin_bit_cast(short, h);
}

// ---------- Kernel 0: W (8.39M) and X (0.52M) f32 -> bf16 ----------
// 2048 blocks x 256 thr = 524288 threads; 16 W floats + (first 65536
// threads) 8 X floats each. All loads/stores 16-B, fully coalesced.
__global__ __launch_bounds__(256)
void cvt_kernel(const float* __restrict__ W0, const float* __restrict__ X,
                ushort* __restrict__ Wb16, ushort* __restrict__ Xb16)
{
    const int t = blockIdx.x * 256 + threadIdx.x;   // 0..524287
#pragma unroll
    for (int q = 0; q < 2; ++q) {
        const size_t base = ((size_t)q * 524288 + t) * 8;
        const float4 v0 = *reinterpret_cast<const float4*>(W0 + base);
        const float4 v1 = *reinterpret_cast<const float4*>(W0 + base + 4);
        short8v s;
        s[0] = f2bf(v0.x); s[1] = f2bf(v0.y); s[2] = f2bf(v0.z); s[3] = f2bf(v0.w);
        s[4] = f2bf(v1.x); s[5] = f2bf(v1.y); s[6] = f2bf(v1.z); s[7] = f2bf(v1.w);
        *reinterpret_cast<short8v*>(Wb16 + base) = s;
    }
    if (t < 65536) {
        const size_t base = (size_t)t * 8;
        const float4 v0 = *reinterpret_cast<const float4*>(X + base);
        const float4 v1 = *reinterpret_cast<const float4*>(X + base + 4);
        short8v s;
        s[0] = f2bf(v0.x); s[1] = f2bf(v0.y); s[2] = f2bf(v0.z); s[3] = f2bf(v0.w);
        s[4] = f2bf(v1.x); s[5] = f2bf(v1.y); s[6] = f2bf(v1.z); s[7] = f2bf(v1.w);
        *reinterpret_cast<short8v*>(Xb16 + base) = s;
    }
}

// ---------- Kernel 1: G[b][n][t] via MFMA, gload_lds bf16 panel ----------
// Block: 256 thr = 4 waves; one 16-row n-tile; wave w owns t-tile w*16.
// LDS swizzle: phys_byte = r*2048 + ((kb*16 + kk*64) ^ ((r&7)<<4)).
__global__ __launch_bounds__(256, 4)
void gemm_kernel(const ushort* __restrict__ Wb16, const ushort* __restrict__ Xb16,
                 float* __restrict__ G)
{
    __shared__ __align__(16) ushort As[16 * 1024];   // 32 KB

    const int lane = threadIdx.x & 63;
    const int wave = threadIdx.x >> 6;
    const int b  = blockIdx.x & 7;       // blockIdx%8 = batch
    const int nt = blockIdx.x >> 3;
    const int n0 = nt * 16;
    const int t0 = wave * 16;

    const int r  = lane & 15;            // fragment row
    const int kb = lane >> 4;            // k-block 0..3 (8 k's each)

    // panel = 16 contiguous bf16 rows (32 KB contiguous in global)
    const char* __restrict__ panel = (const char*)(
        (n0 < NO) ? (Wb16 + ((size_t)b * NO + n0) * NI)
                  : (Xb16 + ((size_t)b * TT + (n0 - NO)) * NI));

    // ---- stage: 32 issues of 1 KB; linear LDS dest, inverse-swizzled
    //      per-lane global source: g = i*1024 + (lane ^ ((i>>1)&7))*16 ----
#pragma unroll
    for (int ii = 0; ii < 8; ++ii) {
        const int i   = wave * 8 + ii;
        const int swz = (i >> 1) & 7;
        const char* src = panel + i * 1024 + ((lane ^ swz) << 4);
        char* dst = (char*)As + i * 1024;           // wave-uniform base
        __builtin_amdgcn_global_load_lds(
            (const __attribute__((address_space(1))) void*)src,
            (__attribute__((address_space(3))) void*)dst,
            16, 0, 0);
    }
    __syncthreads();   // compiler drains vmcnt before barrier

    // ---- swizzled read bases: phys = lanebyte | ((kk^rbit)<<6) + ...
    //      even kk: ApE + (kk/2)*128 ; odd kk: ApO + (kk/2)*128 ----
    const int lanebyte = (r << 11) | ((kb ^ (r & 3)) << 4);
    const int rbit = (r >> 2) & 1;
    const char* ApE = (const char*)As + (lanebyte | (rbit << 6));
    const char* ApO = (const char*)As + (lanebyte | ((rbit ^ 1) << 6));

    const ushort* __restrict__ Bbase =
        Xb16 + ((size_t)b * TT + t0 + r) * NI + kb * 8;

    f32x4 acc = {0.f, 0.f, 0.f, 0.f};
#pragma unroll 8
    for (int kk2 = 0; kk2 < 16; ++kk2) {
        const bf16x8 ae = *reinterpret_cast<const bf16x8*>(ApE + kk2 * 128);
        const bf16x8 be = *reinterpret_cast<const bf16x8*>(Bbase + kk2 * 64);
        acc = __builtin_amdgcn_mfma_f32_16x16x32_bf16(ae, be, acc, 0, 0, 0);
        const bf16x8 ao = *reinterpret_cast<const bf16x8*>(ApO + kk2 * 128);
        const bf16x8 bo = *reinterpret_cast<const bf16x8*>(Bbase + kk2 * 64 + 32);
        acc = __builtin_amdgcn_mfma_f32_16x16x32_bf16(ao, bo, acc, 0, 0, 0);
    }

    // D layout: col t = lane&15, row n = (lane>>4)*4 + rr   [m89-verified]
    const int tcol = lane & 15;
    const int mrow = (lane >> 4) * 4;
#pragma unroll
    for (int rr = 0; rr < 4; ++rr)
        G[((size_t)b * NTOT + n0 + mrow + rr) * TT + t0 + tcol] = acc[rr];
}

// ---------- Kernel 2: lane-parallel projected-Oja scan (R10) ----------
// 512 blocks x 256 thr (4 waves). Block: batch b = bid&7, 16 o-rows.
// Wave: 4 rows. Lane l: r = l&3 (row), jb = l>>2 (j-block of 4).
__global__ __launch_bounds__(256, 8)
void scan_kernel(const float* __restrict__ G, float* __restrict__ out)
{
    __shared__ float Sl[TT][TT];      // 16 KB: S[b]
    __shared__ float ybuf[16][68];    // row-local y trajectories (padded)

    const int tid  = threadIdx.x;
    const int lane = tid & 63;
    const int wave = tid >> 6;
    const int b  = blockIdx.x & 7;
    const int o0 = (blockIdx.x >> 3) * 16;

    // stage S[b] = G rows 1024..1087 (4096 floats; 4 float4 per thread)
    {
        const float4* __restrict__ src =
            reinterpret_cast<const float4*>(G + ((size_t)b * NTOT + NO) * TT);
        float4* dst = reinterpret_cast<float4*>(&Sl[0][0]);
#pragma unroll
        for (int q = 0; q < 4; ++q)
            dst[tid + q * 256] = src[tid + q * 256];
    }

    const int r  = lane & 3;
    const int jb = lane >> 2;
    const int row = o0 + wave * 4 + r;

    const float4 uu = *reinterpret_cast<const float4*>(
        G + ((size_t)b * NTOT + row) * TT + jb * 4);
    float u0 = uu.x, u1 = uu.y, u2 = uu.z, u3 = uu.w;

    __syncthreads();

    const float lr   = 1.0f / 1024.0f;
    const float nL2E = -1.44269504f;
    float y0 = 0.f, y1 = 0.f, y2 = 0.f, y3 = 0.f;

#pragma unroll
    for (int t = 0; t < TT; ++t) {
        const int srcl = (t & 0x3C) | r;
        const float uv = ((t & 3) == 0) ? u0 : ((t & 3) == 1) ? u1
                       : ((t & 3) == 2) ? u2 : u3;
        const float pre = __shfl(uv, srcl, 64);

        const float e = __builtin_amdgcn_exp2f(pre * nL2E);
        const float y = __builtin_amdgcn_rcpf(1.0f + e);

        const bool own = (jb == (t >> 2));
        if ((t & 3) == 0) y0 = own ? y : y0;
        if ((t & 3) == 1) y1 = own ? y : y1;
        if ((t & 3) == 2) y2 = own ? y : y2;
        if ((t & 3) == 3) y3 = own ? y : y3;

        const float c2 = lr * y;
        const float c1 = fmaf(-c2, y, 1.0f);

        const float4 s = *reinterpret_cast<const float4*>(&Sl[t][jb * 4]);
        u0 = fmaf(c1, u0, c2 * s.x);
        u1 = fmaf(c1, u1, c2 * s.y);
        u2 = fmaf(c1, u2, c2 * s.z);
        u3 = fmaf(c1, u3, c2 * s.w);
    }

    {
        float4 yv; yv.x = y0; yv.y = y1; yv.z = y2; yv.w = y3;
        *reinterpret_cast<float4*>(&ybuf[wave * 4 + r][jb * 4]) = yv;
    }
    __syncthreads();

    {
        const int t = tid >> 2;
        const int g = tid & 3;
        float4 ov;
        ov.x = ybuf[g * 4 + 0][t];
        ov.y = ybuf[g * 4 + 1][t];
        ov.z = ybuf[g * 4 + 2][t];
        ov.w = ybuf[g * 4 + 3][t];
        *reinterpret_cast<float4*>(
            &out[(size_t)b * TT * NO + (size_t)t * NO + o0 + g * 4]) = ov;
    }
}

extern "C" void kernel_launch(void* const* d_in, const int* in_sizes, int n_in,
                              void* d_out, int out_size, void* d_ws, size_t ws_size,
                              hipStream_t stream) {
    const float* X  = (const float*)d_in[0];   // [8][64][1024]
    const float* W0 = (const float*)d_in[1];   // [8][1024][1024]
    float* out = (float*)d_out;                // [8][64][1024]

    float*  G    = (float*)d_ws;                          // 2,228,224 B
    ushort* Xb16 = (ushort*)((char*)d_ws + 2228224);      // 1,048,576 B
    ushort* Wb16 = (ushort*)((char*)d_ws + 3276800);      // 16,777,216 B

    cvt_kernel<<<2048, 256, 0, stream>>>(W0, X, Wb16, Xb16);
    gemm_kernel<<<BB * NTILES, 256, 0, stream>>>(Wb16, Xb16, G);
    scan_kernel<<<512, 256, 0, stream>>>(G, out);
}